// Round 1
// baseline (509.613 us; speedup 1.0000x reference)
//
#include <hip/hip_runtime.h>
#include <hip/hip_bf16.h>

#define N_NODES 100000
#define N_EDGES 1600000
#define D 32
#define N_GRAPHS 128

// One lane per (edge, feature): lane = idx & 31 handles feature column,
// idx >> 5 is the edge. Gather x[src] (coalesced 128B per edge-group),
// scatter-atomicAdd into agg[dst].
__global__ void scatter_add_kernel(const float* __restrict__ x,
                                   const int* __restrict__ src,
                                   const int* __restrict__ dst,
                                   float* __restrict__ agg) {
    long long idx = (long long)blockIdx.x * blockDim.x + threadIdx.x;
    int e = (int)(idx >> 5);
    int lane = (int)(idx & 31);
    if (e >= N_EDGES) return;
    int s = src[e];
    int d = dst[e];
    float v = x[(long long)s * D + lane];
    atomicAdd(&agg[(long long)d * D + lane], v);
}

// One 32-lane group per node: h[v] = act((x[v]+agg[v]) @ W + b)
template <bool RELU>
__global__ void node_update_kernel(const float* __restrict__ x,
                                   const float* __restrict__ agg,
                                   const float* __restrict__ W,
                                   const float* __restrict__ b,
                                   float* __restrict__ out) {
    __shared__ float sW[D * D];
    __shared__ float sb[D];
    int t = threadIdx.x;
    for (int i = t; i < D * D; i += blockDim.x) sW[i] = W[i];
    if (t < D) sb[t] = b[t];
    __syncthreads();

    int grp = t >> 5;
    int lane = t & 31;
    int v = blockIdx.x * (blockDim.x >> 5) + grp;
    if (v >= N_NODES) return;

    float xv = x[(long long)v * D + lane] + agg[(long long)v * D + lane];
    float acc = sb[lane];
#pragma unroll
    for (int d = 0; d < D; ++d) {
        float xd = __shfl(xv, d, 32);
        acc += xd * sW[d * D + lane];
    }
    if (RELU) acc = fmaxf(acc, 0.0f);
    out[(long long)v * D + lane] = acc;
}

// Layer-2 linear fused with per-graph sum pooling.
__global__ void node_update_pool_kernel(const float* __restrict__ x,
                                        const float* __restrict__ agg,
                                        const float* __restrict__ W,
                                        const float* __restrict__ b,
                                        const int* __restrict__ graph_ids,
                                        float* __restrict__ out) {
    __shared__ float sW[D * D];
    __shared__ float sb[D];
    int t = threadIdx.x;
    for (int i = t; i < D * D; i += blockDim.x) sW[i] = W[i];
    if (t < D) sb[t] = b[t];
    __syncthreads();

    int grp = t >> 5;
    int lane = t & 31;
    int v = blockIdx.x * (blockDim.x >> 5) + grp;
    if (v >= N_NODES) return;

    float xv = x[(long long)v * D + lane] + agg[(long long)v * D + lane];
    float acc = sb[lane];
#pragma unroll
    for (int d = 0; d < D; ++d) {
        float xd = __shfl(xv, d, 32);
        acc += xd * sW[d * D + lane];
    }
    int g = graph_ids[v];
    atomicAdd(&out[g * D + lane], acc);
}

extern "C" void kernel_launch(void* const* d_in, const int* in_sizes, int n_in,
                              void* d_out, int out_size, void* d_ws, size_t ws_size,
                              hipStream_t stream) {
    const float* feats = (const float*)d_in[0];
    const int* src = (const int*)d_in[1];
    const int* dst = (const int*)d_in[2];
    const int* graph_ids = (const int*)d_in[3];
    const float* W1 = (const float*)d_in[4];
    const float* b1 = (const float*)d_in[5];
    const float* W2 = (const float*)d_in[6];
    const float* b2 = (const float*)d_in[7];
    float* out = (float*)d_out;

    float* agg = (float*)d_ws;                          // N_NODES*D floats
    float* h   = agg + (size_t)N_NODES * D;             // N_NODES*D floats

    const size_t node_bytes = (size_t)N_NODES * D * sizeof(float);

    const int scatter_threads = 256;
    const int scatter_blocks = (N_EDGES * 32 + scatter_threads - 1) / scatter_threads;
    const int node_threads = 256;
    const int nodes_per_block = node_threads / 32;
    const int node_blocks = (N_NODES + nodes_per_block - 1) / nodes_per_block;

    // ---- Layer 1 ----
    hipMemsetAsync(agg, 0, node_bytes, stream);
    scatter_add_kernel<<<scatter_blocks, scatter_threads, 0, stream>>>(feats, src, dst, agg);
    node_update_kernel<true><<<node_blocks, node_threads, 0, stream>>>(feats, agg, W1, b1, h);

    // ---- Layer 2 + pooling ----
    hipMemsetAsync(agg, 0, node_bytes, stream);
    scatter_add_kernel<<<scatter_blocks, scatter_threads, 0, stream>>>(h, src, dst, agg);
    hipMemsetAsync(out, 0, (size_t)out_size * sizeof(float), stream);
    node_update_pool_kernel<<<node_blocks, node_threads, 0, stream>>>(h, agg, W2, b2, graph_ids, out);
}

// Round 2
// 455.961 us; speedup vs baseline: 1.1177x; 1.1177x over previous
//
#include <hip/hip_runtime.h>
#include <hip/hip_bf16.h>

#define N_NODES 100000
#define N_EDGES 1600000
#define D 32
#define N_GRAPHS 128

#define SCAN_CHUNK 1024   // elements per scan block (256 threads x 4)
#define N_CHUNKS ((N_NODES + SCAN_CHUNK - 1) / SCAN_CHUNK)   // 98

// ---- CSR build ----

__global__ void hist_kernel(const int* __restrict__ dst, int* __restrict__ deg) {
    int e = blockIdx.x * blockDim.x + threadIdx.x;
    if (e >= N_EDGES) return;
    atomicAdd(&deg[dst[e]], 1);
}

// Per-chunk inclusive scan; writes inclusive-within-chunk to inc[], chunk total to psum[].
__global__ void scan1_kernel(const int* __restrict__ deg, int* __restrict__ inc,
                             int* __restrict__ psum) {
    __shared__ int s[256];
    int tid = threadIdx.x;
    int base = blockIdx.x * SCAN_CHUNK + tid * 4;
    int v0 = (base + 0 < N_NODES) ? deg[base + 0] : 0;
    int v1 = (base + 1 < N_NODES) ? deg[base + 1] : 0;
    int v2 = (base + 2 < N_NODES) ? deg[base + 2] : 0;
    int v3 = (base + 3 < N_NODES) ? deg[base + 3] : 0;
    int i0 = v0, i1 = v0 + v1, i2 = v0 + v1 + v2, i3 = v0 + v1 + v2 + v3;
    int tsum = i3;
    s[tid] = tsum;
    __syncthreads();
    for (int off = 1; off < 256; off <<= 1) {
        int t = (tid >= off) ? s[tid - off] : 0;
        __syncthreads();
        s[tid] += t;
        __syncthreads();
    }
    int excl = s[tid] - tsum;   // exclusive prefix of this thread within chunk
    if (base + 0 < N_NODES) inc[base + 0] = excl + i0;
    if (base + 1 < N_NODES) inc[base + 1] = excl + i1;
    if (base + 2 < N_NODES) inc[base + 2] = excl + i2;
    if (base + 3 < N_NODES) inc[base + 3] = excl + i3;
    if (tid == 255) psum[blockIdx.x] = s[255];
}

// Exclusive scan of chunk totals (single block; N_CHUNKS <= 256).
__global__ void scan2_kernel(int* __restrict__ psum) {
    __shared__ int s[256];
    int tid = threadIdx.x;
    int v = (tid < N_CHUNKS) ? psum[tid] : 0;
    s[tid] = v;
    __syncthreads();
    for (int off = 1; off < 256; off <<= 1) {
        int t = (tid >= off) ? s[tid - off] : 0;
        __syncthreads();
        s[tid] += t;
        __syncthreads();
    }
    if (tid < N_CHUNKS) psum[tid] = s[tid] - v;   // exclusive
}

// Add chunk offsets; produce cursor[] = row start.
__global__ void scan3_kernel(int* __restrict__ inc, const int* __restrict__ deg,
                             const int* __restrict__ psum, int* __restrict__ cursor) {
    int i = blockIdx.x * blockDim.x + threadIdx.x;
    if (i >= N_NODES) return;
    int val = inc[i] + psum[i >> 10];
    inc[i] = val;                 // inclusive scan (row end)
    cursor[i] = val - deg[i];     // row start
}

__global__ void reorder_kernel(const int* __restrict__ src, const int* __restrict__ dst,
                               int* __restrict__ cursor, int* __restrict__ esrc) {
    int e = blockIdx.x * blockDim.x + threadIdx.x;
    if (e >= N_EDGES) return;
    int d = dst[e];
    int p = atomicAdd(&cursor[d], 1);
    esrc[p] = src[e];
}

// ---- Fused GIN layer: pull-aggregate + linear (+ReLU or +graph-pool) ----
// One 32-lane group per node; lane = feature column.
template <bool RELU, bool POOL>
__global__ void gin_layer_kernel(const float* __restrict__ x,
                                 const int* __restrict__ esrc,
                                 const int* __restrict__ inc,
                                 const int* __restrict__ deg,
                                 const float* __restrict__ W,
                                 const float* __restrict__ b,
                                 const int* __restrict__ graph_ids,
                                 float* __restrict__ out) {
    __shared__ float sW[D * D];
    __shared__ float sb[D];
    int t = threadIdx.x;
    for (int i = t; i < D * D; i += blockDim.x) sW[i] = W[i];
    if (t < D) sb[t] = b[t];
    __syncthreads();

    int grp = t >> 5;
    int lane = t & 31;
    int v = blockIdx.x * (blockDim.x >> 5) + grp;
    if (v >= N_NODES) return;

    int end = inc[v];
    int e = end - deg[v];

    float acc = x[(size_t)v * D + lane];   // self term (eps = 0)
    // 4-way unrolled gather for memory-level parallelism
    for (; e + 4 <= end; e += 4) {
        int s0 = esrc[e], s1 = esrc[e + 1], s2 = esrc[e + 2], s3 = esrc[e + 3];
        float a0 = x[(size_t)s0 * D + lane];
        float a1 = x[(size_t)s1 * D + lane];
        float a2 = x[(size_t)s2 * D + lane];
        float a3 = x[(size_t)s3 * D + lane];
        acc += a0 + a1 + a2 + a3;
    }
    for (; e < end; ++e) acc += x[(size_t)esrc[e] * D + lane];

    // y_lane = b[lane] + sum_d acc_d * W[d][lane]
    float y = sb[lane];
#pragma unroll
    for (int d = 0; d < D; ++d) {
        y += __shfl(acc, d, 32) * sW[d * D + lane];
    }
    if (RELU) y = fmaxf(y, 0.0f);
    if (POOL) {
        atomicAdd(&out[graph_ids[v] * D + lane], y);
    } else {
        out[(size_t)v * D + lane] = y;
    }
}

extern "C" void kernel_launch(void* const* d_in, const int* in_sizes, int n_in,
                              void* d_out, int out_size, void* d_ws, size_t ws_size,
                              hipStream_t stream) {
    const float* feats = (const float*)d_in[0];
    const int* src = (const int*)d_in[1];
    const int* dst = (const int*)d_in[2];
    const int* graph_ids = (const int*)d_in[3];
    const float* W1 = (const float*)d_in[4];
    const float* b1 = (const float*)d_in[5];
    const float* W2 = (const float*)d_in[6];
    const float* b2 = (const float*)d_in[7];
    float* out = (float*)d_out;

    // Workspace layout (ints are 4B)
    int* deg    = (int*)d_ws;                     // N_NODES
    int* inc    = deg + N_NODES;                  // N_NODES
    int* cursor = inc + N_NODES;                  // N_NODES
    int* psum   = cursor + N_NODES;               // 256
    int* esrc   = psum + 256;                     // N_EDGES
    float* h    = (float*)(esrc + N_EDGES);       // N_NODES * D

    const int edge_blocks = (N_EDGES + 255) / 256;
    const int node_blocks256 = (N_NODES + 255) / 256;
    const int nodes_per_block = 256 / 32;
    const int layer_blocks = (N_NODES + nodes_per_block - 1) / nodes_per_block;

    // ---- Build CSR (dst-sorted) once; reused by both layers ----
    hipMemsetAsync(deg, 0, (size_t)N_NODES * sizeof(int), stream);
    hist_kernel<<<edge_blocks, 256, 0, stream>>>(dst, deg);
    scan1_kernel<<<N_CHUNKS, 256, 0, stream>>>(deg, inc, psum);
    scan2_kernel<<<1, 256, 0, stream>>>(psum);
    scan3_kernel<<<node_blocks256, 256, 0, stream>>>(inc, deg, psum, cursor);
    reorder_kernel<<<edge_blocks, 256, 0, stream>>>(src, dst, cursor, esrc);

    // ---- Layer 1: h = relu((x + agg(x)) @ W1 + b1) ----
    gin_layer_kernel<true, false><<<layer_blocks, 256, 0, stream>>>(
        feats, esrc, inc, deg, W1, b1, graph_ids, h);

    // ---- Layer 2 + sum pooling ----
    hipMemsetAsync(out, 0, (size_t)out_size * sizeof(float), stream);
    gin_layer_kernel<false, true><<<layer_blocks, 256, 0, stream>>>(
        h, esrc, inc, deg, W2, b2, graph_ids, out);
}

// Round 3
// 308.304 us; speedup vs baseline: 1.6530x; 1.4789x over previous
//
#include <hip/hip_runtime.h>
#include <hip/hip_bf16.h>

#define N_NODES 100000
#define N_EDGES 1600000
#define D 32
#define N_GRAPHS 128

#define SCAN_CHUNK 1024
#define N_CHUNKS ((N_NODES + SCAN_CHUNK - 1) / SCAN_CHUNK)   // 98
#define NODES_PER_WAVE 8

// ---- CSR build ----

__global__ void hist_kernel(const int* __restrict__ dst, int* __restrict__ deg) {
    int e = blockIdx.x * blockDim.x + threadIdx.x;
    if (e >= N_EDGES) return;
    atomicAdd(&deg[dst[e]], 1);
}

// Per-chunk inclusive scan; inclusive-within-chunk to inc[], chunk total to psum[].
__global__ void scan1_kernel(const int* __restrict__ deg, int* __restrict__ inc,
                             int* __restrict__ psum) {
    __shared__ int s[256];
    int tid = threadIdx.x;
    int base = blockIdx.x * SCAN_CHUNK + tid * 4;
    int v0 = (base + 0 < N_NODES) ? deg[base + 0] : 0;
    int v1 = (base + 1 < N_NODES) ? deg[base + 1] : 0;
    int v2 = (base + 2 < N_NODES) ? deg[base + 2] : 0;
    int v3 = (base + 3 < N_NODES) ? deg[base + 3] : 0;
    int i0 = v0, i1 = v0 + v1, i2 = v0 + v1 + v2, i3 = v0 + v1 + v2 + v3;
    int tsum = i3;
    s[tid] = tsum;
    __syncthreads();
    for (int off = 1; off < 256; off <<= 1) {
        int t = (tid >= off) ? s[tid - off] : 0;
        __syncthreads();
        s[tid] += t;
        __syncthreads();
    }
    int excl = s[tid] - tsum;
    if (base + 0 < N_NODES) inc[base + 0] = excl + i0;
    if (base + 1 < N_NODES) inc[base + 1] = excl + i1;
    if (base + 2 < N_NODES) inc[base + 2] = excl + i2;
    if (base + 3 < N_NODES) inc[base + 3] = excl + i3;
    if (tid == 255) psum[blockIdx.x] = s[255];
}

// Fused: add exclusive chunk-offset (computed per block from psum) and emit cursor.
__global__ void scan23_kernel(int* __restrict__ inc, const int* __restrict__ deg,
                              const int* __restrict__ psum, int* __restrict__ cursor) {
    __shared__ int s[128];
    int t = threadIdx.x;
    int i = blockIdx.x * 256 + t;
    int chunk = blockIdx.x >> 2;           // 256 | 1024, so uniform per block
    if (t < 128) s[t] = (t < chunk) ? psum[t] : 0;   // chunk <= 97 < 128
    __syncthreads();
    for (int off = 64; off > 0; off >>= 1) {
        if (t < off) s[t] += s[t + off];
        __syncthreads();
    }
    int offset = s[0];
    if (i < N_NODES) {
        int val = inc[i] + offset;
        inc[i] = val;                 // row end
        cursor[i] = val - deg[i];     // row start
    }
}

__global__ void reorder_kernel(const int* __restrict__ src, const int* __restrict__ dst,
                               int* __restrict__ cursor, int* __restrict__ esrc) {
    int e = blockIdx.x * blockDim.x + threadIdx.x;
    if (e >= N_EDGES) return;
    int d = dst[e];
    int p = atomicAdd(&cursor[d], 1);
    esrc[p] = src[e];
}

// ---- Fused GIN layer ----
// Wave (64 lanes) = 8 edge-slots (es) x 8 feature-quads (fq). One gather
// instruction moves 8 edges x 128B. W lives in registers: each lane holds the
// 4x4 fragment W[es*4+k][fq*4+c]. Each wave owns a contiguous 8-node range.
template <bool RELU, bool POOL>
__global__ void gin_layer_kernel(const float* __restrict__ x,
                                 const int* __restrict__ esrc,
                                 const int* __restrict__ rend,
                                 const int* __restrict__ deg,
                                 const float* __restrict__ W,
                                 const float* __restrict__ b,
                                 const int* __restrict__ graph_ids,
                                 float* __restrict__ out) {
    const int lane = threadIdx.x & 63;
    const int es = lane >> 3;
    const int fq = lane & 7;

    float w[4][4];
#pragma unroll
    for (int k = 0; k < 4; ++k) {
        const float4 wv = *reinterpret_cast<const float4*>(&W[(es * 4 + k) * D + fq * 4]);
        w[k][0] = wv.x; w[k][1] = wv.y; w[k][2] = wv.z; w[k][3] = wv.w;
    }
    const float4 bv = *reinterpret_cast<const float4*>(&b[fq * 4]);

    const int wid = blockIdx.x * (blockDim.x >> 6) + (threadIdx.x >> 6);
    const int v0 = wid * NODES_PER_WAVE;
    if (v0 >= N_NODES) return;
    const int v1 = (v0 + NODES_PER_WAVE < N_NODES) ? v0 + NODES_PER_WAVE : N_NODES;

    float p0 = 0.f, p1 = 0.f, p2 = 0.f, p3 = 0.f;   // pool accumulator
    int cur_g = POOL ? graph_ids[v0] : 0;

    for (int v = v0; v < v1; ++v) {
        const int end = rend[v];
        const int dg = deg[v];
        int e = end - dg;

        float a0, a1, a2, a3;
        if (es == 0) {   // self term (eps = 0)
            const float4 xv = *reinterpret_cast<const float4*>(&x[(size_t)v * D + fq * 4]);
            a0 = xv.x; a1 = xv.y; a2 = xv.z; a3 = xv.w;
        } else { a0 = a1 = a2 = a3 = 0.f; }

        // 16 edges in flight per iteration (2 x 8-edge gathers)
        for (; e + 16 <= end; e += 16) {
            const int s0 = esrc[e + es];
            const int s1 = esrc[e + 8 + es];
            const float4 g0 = *reinterpret_cast<const float4*>(&x[(size_t)s0 * D + fq * 4]);
            const float4 g1 = *reinterpret_cast<const float4*>(&x[(size_t)s1 * D + fq * 4]);
            a0 += g0.x; a1 += g0.y; a2 += g0.z; a3 += g0.w;
            a0 += g1.x; a1 += g1.y; a2 += g1.z; a3 += g1.w;
        }
        if (e + 8 <= end) {
            const int s0 = esrc[e + es];
            const float4 g0 = *reinterpret_cast<const float4*>(&x[(size_t)s0 * D + fq * 4]);
            a0 += g0.x; a1 += g0.y; a2 += g0.z; a3 += g0.w;
            e += 8;
        }
        const int rem = end - e;   // 0..7
        if (es < rem) {
            const int s0 = esrc[e + es];
            const float4 g0 = *reinterpret_cast<const float4*>(&x[(size_t)s0 * D + fq * 4]);
            a0 += g0.x; a1 += g0.y; a2 += g0.z; a3 += g0.w;
        }

        // reduce partials across es-groups (flip lane bits 3..5)
        a0 += __shfl_xor(a0, 8);  a1 += __shfl_xor(a1, 8);  a2 += __shfl_xor(a2, 8);  a3 += __shfl_xor(a3, 8);
        a0 += __shfl_xor(a0, 16); a1 += __shfl_xor(a1, 16); a2 += __shfl_xor(a2, 16); a3 += __shfl_xor(a3, 16);
        a0 += __shfl_xor(a0, 32); a1 += __shfl_xor(a1, 16 * 2); a2 += __shfl_xor(a2, 32); a3 += __shfl_xor(a3, 32);

        // group es grabs input-quad es (held by the lane with fq == es)
        const float q0 = __shfl(a0, es, 8);
        const float q1 = __shfl(a1, es, 8);
        const float q2 = __shfl(a2, es, 8);
        const float q3 = __shfl(a3, es, 8);

        // partial matvec: contribution of input rows es*4..es*4+3 to out quad fq
        float y0 = q0 * w[0][0] + q1 * w[1][0] + q2 * w[2][0] + q3 * w[3][0];
        float y1 = q0 * w[0][1] + q1 * w[1][1] + q2 * w[2][1] + q3 * w[3][1];
        float y2 = q0 * w[0][2] + q1 * w[1][2] + q2 * w[2][2] + q3 * w[3][2];
        float y3 = q0 * w[0][3] + q1 * w[1][3] + q2 * w[2][3] + q3 * w[3][3];

        y0 += __shfl_xor(y0, 8);  y1 += __shfl_xor(y1, 8);  y2 += __shfl_xor(y2, 8);  y3 += __shfl_xor(y3, 8);
        y0 += __shfl_xor(y0, 16); y1 += __shfl_xor(y1, 16); y2 += __shfl_xor(y2, 16); y3 += __shfl_xor(y3, 16);
        y0 += __shfl_xor(y0, 32); y1 += __shfl_xor(y1, 32); y2 += __shfl_xor(y2, 32); y3 += __shfl_xor(y3, 32);

        y0 += bv.x; y1 += bv.y; y2 += bv.z; y3 += bv.w;
        if (RELU) {
            y0 = fmaxf(y0, 0.f); y1 = fmaxf(y1, 0.f); y2 = fmaxf(y2, 0.f); y3 = fmaxf(y3, 0.f);
        }

        if (POOL) {
            const int g = graph_ids[v];
            if (g != cur_g) {
                if (es == 0) {
                    atomicAdd(&out[cur_g * D + fq * 4 + 0], p0);
                    atomicAdd(&out[cur_g * D + fq * 4 + 1], p1);
                    atomicAdd(&out[cur_g * D + fq * 4 + 2], p2);
                    atomicAdd(&out[cur_g * D + fq * 4 + 3], p3);
                }
                p0 = p1 = p2 = p3 = 0.f;
                cur_g = g;
            }
            p0 += y0; p1 += y1; p2 += y2; p3 += y3;
        } else {
            if (es == 0) {
                float4 o; o.x = y0; o.y = y1; o.z = y2; o.w = y3;
                *reinterpret_cast<float4*>(&out[(size_t)v * D + fq * 4]) = o;
            }
        }
    }
    if (POOL) {
        if (es == 0) {
            atomicAdd(&out[cur_g * D + fq * 4 + 0], p0);
            atomicAdd(&out[cur_g * D + fq * 4 + 1], p1);
            atomicAdd(&out[cur_g * D + fq * 4 + 2], p2);
            atomicAdd(&out[cur_g * D + fq * 4 + 3], p3);
        }
    }
}

extern "C" void kernel_launch(void* const* d_in, const int* in_sizes, int n_in,
                              void* d_out, int out_size, void* d_ws, size_t ws_size,
                              hipStream_t stream) {
    const float* feats = (const float*)d_in[0];
    const int* src = (const int*)d_in[1];
    const int* dst = (const int*)d_in[2];
    const int* graph_ids = (const int*)d_in[3];
    const float* W1 = (const float*)d_in[4];
    const float* b1 = (const float*)d_in[5];
    const float* W2 = (const float*)d_in[6];
    const float* b2 = (const float*)d_in[7];
    float* out = (float*)d_out;

    int* deg    = (int*)d_ws;                     // N_NODES
    int* inc    = deg + N_NODES;                  // N_NODES (row end)
    int* cursor = inc + N_NODES;                  // N_NODES
    int* psum   = cursor + N_NODES;               // 256
    int* esrc   = psum + 256;                     // N_EDGES
    float* h    = (float*)(esrc + N_EDGES);       // N_NODES * D

    const int edge_blocks = (N_EDGES + 255) / 256;
    const int scan3_blocks = (N_NODES + 255) / 256;
    const int total_waves = (N_NODES + NODES_PER_WAVE - 1) / NODES_PER_WAVE;  // 12500
    const int layer_blocks = (total_waves + 3) / 4;                            // 4 waves/block

    // ---- Build CSR (dst-sorted), reused by both layers ----
    hipMemsetAsync(deg, 0, (size_t)N_NODES * sizeof(int), stream);
    hist_kernel<<<edge_blocks, 256, 0, stream>>>(dst, deg);
    scan1_kernel<<<N_CHUNKS, 256, 0, stream>>>(deg, inc, psum);
    scan23_kernel<<<scan3_blocks, 256, 0, stream>>>(inc, deg, psum, cursor);
    reorder_kernel<<<edge_blocks, 256, 0, stream>>>(src, dst, cursor, esrc);

    // ---- Layer 1: h = relu((x + agg(x)) @ W1 + b1) ----
    gin_layer_kernel<true, false><<<layer_blocks, 256, 0, stream>>>(
        feats, esrc, inc, deg, W1, b1, graph_ids, h);

    // ---- Layer 2 + sum pooling ----
    hipMemsetAsync(out, 0, (size_t)out_size * sizeof(float), stream);
    gin_layer_kernel<false, true><<<layer_blocks, 256, 0, stream>>>(
        h, esrc, inc, deg, W2, b2, graph_ids, out);
}

// Round 4
// 268.007 us; speedup vs baseline: 1.9015x; 1.1504x over previous
//
#include <hip/hip_runtime.h>
#include <hip/hip_bf16.h>

#define N_NODES 100000
#define N_EDGES 1600000
#define D 32
#define N_GRAPHS 128

#define SCAN_CHUNK 1024
#define N_CHUNKS ((N_NODES + SCAN_CHUNK - 1) / SCAN_CHUNK)   // 98
#define NODES_PER_WAVE 8

#define NPASS 8
#define NODES_PER_PASS ((N_NODES + NPASS - 1) / NPASS)       // 12500

// ---- CSR build ----

__global__ void hist_kernel(const int* __restrict__ dst, int* __restrict__ deg) {
    int e = blockIdx.x * blockDim.x + threadIdx.x;
    if (e >= N_EDGES) return;
    atomicAdd(&deg[dst[e]], 1);
}

// Per-chunk inclusive scan; inclusive-within-chunk to inc[], chunk total to psum[].
__global__ void scan1_kernel(const int* __restrict__ deg, int* __restrict__ inc,
                             int* __restrict__ psum) {
    __shared__ int s[256];
    int tid = threadIdx.x;
    int base = blockIdx.x * SCAN_CHUNK + tid * 4;
    int v0 = (base + 0 < N_NODES) ? deg[base + 0] : 0;
    int v1 = (base + 1 < N_NODES) ? deg[base + 1] : 0;
    int v2 = (base + 2 < N_NODES) ? deg[base + 2] : 0;
    int v3 = (base + 3 < N_NODES) ? deg[base + 3] : 0;
    int i0 = v0, i1 = v0 + v1, i2 = v0 + v1 + v2, i3 = v0 + v1 + v2 + v3;
    int tsum = i3;
    s[tid] = tsum;
    __syncthreads();
    for (int off = 1; off < 256; off <<= 1) {
        int t = (tid >= off) ? s[tid - off] : 0;
        __syncthreads();
        s[tid] += t;
        __syncthreads();
    }
    int excl = s[tid] - tsum;
    if (base + 0 < N_NODES) inc[base + 0] = excl + i0;
    if (base + 1 < N_NODES) inc[base + 1] = excl + i1;
    if (base + 2 < N_NODES) inc[base + 2] = excl + i2;
    if (base + 3 < N_NODES) inc[base + 3] = excl + i3;
    if (tid == 255) psum[blockIdx.x] = s[255];
}

// Fused: add exclusive chunk-offset (computed per block from psum) and emit cursor.
__global__ void scan23_kernel(int* __restrict__ inc, const int* __restrict__ deg,
                              const int* __restrict__ psum, int* __restrict__ cursor) {
    __shared__ int s[128];
    int t = threadIdx.x;
    int i = blockIdx.x * 256 + t;
    int chunk = blockIdx.x >> 2;           // 256 | 1024, so uniform per block
    if (t < 128) s[t] = (t < chunk) ? psum[t] : 0;   // chunk <= 97 < 128
    __syncthreads();
    for (int off = 64; off > 0; off >>= 1) {
        if (t < off) s[t] += s[t + off];
        __syncthreads();
    }
    int offset = s[0];
    if (i < N_NODES) {
        int val = inc[i] + offset;
        inc[i] = val;                 // row end
        cursor[i] = val - deg[i];     // row start
    }
}

// Dst-range-partitioned reorder: each block keeps its edge chunk L1-resident
// and loops over NPASS dst windows, so the scattered esrc writes of a pass fit
// in per-XCD L2 (800KB << 4MB) -> full-line writebacks instead of 16x
// write amplification. Pure locality optimization; atomics keep it correct
// under any interleaving.
__global__ void reorder_part_kernel(const int* __restrict__ src,
                                    const int* __restrict__ dst,
                                    int* __restrict__ cursor,
                                    int* __restrict__ esrc) {
    const int chunk = (N_EDGES + gridDim.x - 1) / gridDim.x;
    const int e0 = blockIdx.x * chunk;
    const int e1 = (e0 + chunk < N_EDGES) ? e0 + chunk : N_EDGES;
    for (int pass = 0; pass < NPASS; ++pass) {
        const int lo = pass * NODES_PER_PASS;
        const int hi = lo + NODES_PER_PASS;
        for (int e = e0 + threadIdx.x; e < e1; e += blockDim.x) {
            int d = dst[e];
            if (d >= lo && d < hi) {
                int p = atomicAdd(&cursor[d], 1);
                esrc[p] = src[e];
            }
        }
    }
}

// ---- Fused GIN layer ----
// Wave (64 lanes) = 8 edge-slots (es) x 8 feature-quads (fq). One gather
// instruction moves 8 edges x 128B. W lives in registers: each lane holds the
// 4x4 fragment W[es*4+k][fq*4+c]. Each wave owns a contiguous 8-node range.
template <bool RELU, bool POOL>
__global__ void gin_layer_kernel(const float* __restrict__ x,
                                 const int* __restrict__ esrc,
                                 const int* __restrict__ rend,
                                 const int* __restrict__ deg,
                                 const float* __restrict__ W,
                                 const float* __restrict__ b,
                                 const int* __restrict__ graph_ids,
                                 float* __restrict__ out) {
    const int lane = threadIdx.x & 63;
    const int es = lane >> 3;
    const int fq = lane & 7;

    float w[4][4];
#pragma unroll
    for (int k = 0; k < 4; ++k) {
        const float4 wv = *reinterpret_cast<const float4*>(&W[(es * 4 + k) * D + fq * 4]);
        w[k][0] = wv.x; w[k][1] = wv.y; w[k][2] = wv.z; w[k][3] = wv.w;
    }
    const float4 bv = *reinterpret_cast<const float4*>(&b[fq * 4]);

    const int wid = blockIdx.x * (blockDim.x >> 6) + (threadIdx.x >> 6);
    const int v0 = wid * NODES_PER_WAVE;
    if (v0 >= N_NODES) return;
    const int v1 = (v0 + NODES_PER_WAVE < N_NODES) ? v0 + NODES_PER_WAVE : N_NODES;

    float p0 = 0.f, p1 = 0.f, p2 = 0.f, p3 = 0.f;   // pool accumulator
    int cur_g = POOL ? graph_ids[v0] : 0;

    for (int v = v0; v < v1; ++v) {
        const int end = rend[v];
        const int dg = deg[v];
        int e = end - dg;

        float a0, a1, a2, a3;
        if (es == 0) {   // self term (eps = 0)
            const float4 xv = *reinterpret_cast<const float4*>(&x[(size_t)v * D + fq * 4]);
            a0 = xv.x; a1 = xv.y; a2 = xv.z; a3 = xv.w;
        } else { a0 = a1 = a2 = a3 = 0.f; }

        // 16 edges in flight per iteration (2 x 8-edge gathers)
        for (; e + 16 <= end; e += 16) {
            const int s0 = esrc[e + es];
            const int s1 = esrc[e + 8 + es];
            const float4 g0 = *reinterpret_cast<const float4*>(&x[(size_t)s0 * D + fq * 4]);
            const float4 g1 = *reinterpret_cast<const float4*>(&x[(size_t)s1 * D + fq * 4]);
            a0 += g0.x; a1 += g0.y; a2 += g0.z; a3 += g0.w;
            a0 += g1.x; a1 += g1.y; a2 += g1.z; a3 += g1.w;
        }
        if (e + 8 <= end) {
            const int s0 = esrc[e + es];
            const float4 g0 = *reinterpret_cast<const float4*>(&x[(size_t)s0 * D + fq * 4]);
            a0 += g0.x; a1 += g0.y; a2 += g0.z; a3 += g0.w;
            e += 8;
        }
        const int rem = end - e;   // 0..7
        if (es < rem) {
            const int s0 = esrc[e + es];
            const float4 g0 = *reinterpret_cast<const float4*>(&x[(size_t)s0 * D + fq * 4]);
            a0 += g0.x; a1 += g0.y; a2 += g0.z; a3 += g0.w;
        }

        // reduce partials across es-groups (flip lane bits 3..5)
        a0 += __shfl_xor(a0, 8);  a1 += __shfl_xor(a1, 8);  a2 += __shfl_xor(a2, 8);  a3 += __shfl_xor(a3, 8);
        a0 += __shfl_xor(a0, 16); a1 += __shfl_xor(a1, 16); a2 += __shfl_xor(a2, 16); a3 += __shfl_xor(a3, 16);
        a0 += __shfl_xor(a0, 32); a1 += __shfl_xor(a1, 32); a2 += __shfl_xor(a2, 32); a3 += __shfl_xor(a3, 32);

        // group es grabs input-quad es (held by the lane with fq == es)
        const float q0 = __shfl(a0, es, 8);
        const float q1 = __shfl(a1, es, 8);
        const float q2 = __shfl(a2, es, 8);
        const float q3 = __shfl(a3, es, 8);

        // partial matvec: contribution of input rows es*4..es*4+3 to out quad fq
        float y0 = q0 * w[0][0] + q1 * w[1][0] + q2 * w[2][0] + q3 * w[3][0];
        float y1 = q0 * w[0][1] + q1 * w[1][1] + q2 * w[2][1] + q3 * w[3][1];
        float y2 = q0 * w[0][2] + q1 * w[1][2] + q2 * w[2][2] + q3 * w[3][2];
        float y3 = q0 * w[0][3] + q1 * w[1][3] + q2 * w[2][3] + q3 * w[3][3];

        y0 += __shfl_xor(y0, 8);  y1 += __shfl_xor(y1, 8);  y2 += __shfl_xor(y2, 8);  y3 += __shfl_xor(y3, 8);
        y0 += __shfl_xor(y0, 16); y1 += __shfl_xor(y1, 16); y2 += __shfl_xor(y2, 16); y3 += __shfl_xor(y3, 16);
        y0 += __shfl_xor(y0, 32); y1 += __shfl_xor(y1, 32); y2 += __shfl_xor(y2, 32); y3 += __shfl_xor(y3, 32);

        y0 += bv.x; y1 += bv.y; y2 += bv.z; y3 += bv.w;
        if (RELU) {
            y0 = fmaxf(y0, 0.f); y1 = fmaxf(y1, 0.f); y2 = fmaxf(y2, 0.f); y3 = fmaxf(y3, 0.f);
        }

        if (POOL) {
            const int g = graph_ids[v];
            if (g != cur_g) {
                if (es == 0) {
                    atomicAdd(&out[cur_g * D + fq * 4 + 0], p0);
                    atomicAdd(&out[cur_g * D + fq * 4 + 1], p1);
                    atomicAdd(&out[cur_g * D + fq * 4 + 2], p2);
                    atomicAdd(&out[cur_g * D + fq * 4 + 3], p3);
                }
                p0 = p1 = p2 = p3 = 0.f;
                cur_g = g;
            }
            p0 += y0; p1 += y1; p2 += y2; p3 += y3;
        } else {
            if (es == 0) {
                float4 o; o.x = y0; o.y = y1; o.z = y2; o.w = y3;
                *reinterpret_cast<float4*>(&out[(size_t)v * D + fq * 4]) = o;
            }
        }
    }
    if (POOL) {
        if (es == 0) {
            atomicAdd(&out[cur_g * D + fq * 4 + 0], p0);
            atomicAdd(&out[cur_g * D + fq * 4 + 1], p1);
            atomicAdd(&out[cur_g * D + fq * 4 + 2], p2);
            atomicAdd(&out[cur_g * D + fq * 4 + 3], p3);
        }
    }
}

extern "C" void kernel_launch(void* const* d_in, const int* in_sizes, int n_in,
                              void* d_out, int out_size, void* d_ws, size_t ws_size,
                              hipStream_t stream) {
    const float* feats = (const float*)d_in[0];
    const int* src = (const int*)d_in[1];
    const int* dst = (const int*)d_in[2];
    const int* graph_ids = (const int*)d_in[3];
    const float* W1 = (const float*)d_in[4];
    const float* b1 = (const float*)d_in[5];
    const float* W2 = (const float*)d_in[6];
    const float* b2 = (const float*)d_in[7];
    float* out = (float*)d_out;

    int* deg    = (int*)d_ws;                     // N_NODES
    int* inc    = deg + N_NODES;                  // N_NODES (row end)
    int* cursor = inc + N_NODES;                  // N_NODES
    int* psum   = cursor + N_NODES;               // 256
    int* esrc   = psum + 256;                     // N_EDGES
    float* h    = (float*)(esrc + N_EDGES);       // N_NODES * D

    const int edge_blocks = (N_EDGES + 255) / 256;
    const int scan3_blocks = (N_NODES + 255) / 256;
    const int total_waves = (N_NODES + NODES_PER_WAVE - 1) / NODES_PER_WAVE;  // 12500
    const int layer_blocks = (total_waves + 3) / 4;                            // 4 waves/block

    // ---- Build CSR (dst-sorted), reused by both layers ----
    hipMemsetAsync(deg, 0, (size_t)N_NODES * sizeof(int), stream);
    hist_kernel<<<edge_blocks, 256, 0, stream>>>(dst, deg);
    scan1_kernel<<<N_CHUNKS, 256, 0, stream>>>(deg, inc, psum);
    scan23_kernel<<<scan3_blocks, 256, 0, stream>>>(inc, deg, psum, cursor);
    reorder_part_kernel<<<1024, 256, 0, stream>>>(src, dst, cursor, esrc);

    // ---- Layer 1: h = relu((x + agg(x)) @ W1 + b1) ----
    gin_layer_kernel<true, false><<<layer_blocks, 256, 0, stream>>>(
        feats, esrc, inc, deg, W1, b1, graph_ids, h);

    // ---- Layer 2 + sum pooling ----
    hipMemsetAsync(out, 0, (size_t)out_size * sizeof(float), stream);
    gin_layer_kernel<false, true><<<layer_blocks, 256, 0, stream>>>(
        h, esrc, inc, deg, W2, b2, graph_ids, out);
}

// Round 5
// 250.674 us; speedup vs baseline: 2.0330x; 1.0691x over previous
//
#include <hip/hip_runtime.h>
#include <hip/hip_bf16.h>

#define N_NODES 100000
#define N_EDGES 1600000
#define D 32
#define N_GRAPHS 128

#define SCAN_CHUNK 1024
#define N_CHUNKS ((N_NODES + SCAN_CHUNK - 1) / SCAN_CHUNK)   // 98
#define NODES_PER_WAVE 8

#define NWIN 8
#define NODES_PER_WIN ((N_NODES + NWIN - 1) / NWIN)          // 12500

// ---- CSR build ----

__global__ void hist_kernel(const int* __restrict__ dst, int* __restrict__ deg) {
    int e = blockIdx.x * blockDim.x + threadIdx.x;
    if (e >= N_EDGES) return;
    atomicAdd(&deg[dst[e]], 1);
}

// Per-chunk inclusive scan; inclusive-within-chunk to inc[], chunk total to psum[].
__global__ void scan1_kernel(const int* __restrict__ deg, int* __restrict__ inc,
                             int* __restrict__ psum) {
    __shared__ int s[256];
    int tid = threadIdx.x;
    int base = blockIdx.x * SCAN_CHUNK + tid * 4;
    int v0 = (base + 0 < N_NODES) ? deg[base + 0] : 0;
    int v1 = (base + 1 < N_NODES) ? deg[base + 1] : 0;
    int v2 = (base + 2 < N_NODES) ? deg[base + 2] : 0;
    int v3 = (base + 3 < N_NODES) ? deg[base + 3] : 0;
    int i0 = v0, i1 = v0 + v1, i2 = v0 + v1 + v2, i3 = v0 + v1 + v2 + v3;
    int tsum = i3;
    s[tid] = tsum;
    __syncthreads();
    for (int off = 1; off < 256; off <<= 1) {
        int t = (tid >= off) ? s[tid - off] : 0;
        __syncthreads();
        s[tid] += t;
        __syncthreads();
    }
    int excl = s[tid] - tsum;
    if (base + 0 < N_NODES) inc[base + 0] = excl + i0;
    if (base + 1 < N_NODES) inc[base + 1] = excl + i1;
    if (base + 2 < N_NODES) inc[base + 2] = excl + i2;
    if (base + 3 < N_NODES) inc[base + 3] = excl + i3;
    if (tid == 255) psum[blockIdx.x] = s[255];
}

// Fused: add exclusive chunk-offset (computed per block from psum) and emit cursor.
__global__ void scan23_kernel(int* __restrict__ inc, const int* __restrict__ deg,
                              const int* __restrict__ psum, int* __restrict__ cursor) {
    __shared__ int s[128];
    int t = threadIdx.x;
    int i = blockIdx.x * 256 + t;
    int chunk = blockIdx.x >> 2;           // 256 | 1024, so uniform per block
    if (t < 128) s[t] = (t < chunk) ? psum[t] : 0;   // chunk <= 97 < 128
    __syncthreads();
    for (int off = 64; off > 0; off >>= 1) {
        if (t < off) s[t] += s[t + off];
        __syncthreads();
    }
    int offset = s[0];
    if (i < N_NODES) {
        int val = inc[i] + offset;
        inc[i] = val;                 // row end
        cursor[i] = val - deg[i];     // row start
    }
}

// XCD-exclusive windowed reorder: block (chunk = bid>>3, win = bid&7).
// With round-robin blockIdx->XCD dispatch, all blocks of window w sit on one
// XCD, so w's 800KB esrc range is written by exactly one XCD -> lines merge
// fully in its L2 -> full-line writebacks (fixes the 14x partial-line write
// amplification seen when all 8 XCDs wrote every window). Reads of the edge
// list happen 8x but 7 are served by the shared L3. Correct under ANY
// block->XCD mapping: every chunk is scanned once per window.
__global__ void reorder_win_kernel(const int* __restrict__ src,
                                   const int* __restrict__ dst,
                                   int* __restrict__ cursor,
                                   int* __restrict__ esrc) {
    const int win = blockIdx.x & (NWIN - 1);
    const int chunk = blockIdx.x >> 3;
    const int nchunk = gridDim.x >> 3;
    const int per = (N_EDGES + nchunk - 1) / nchunk;
    const int e0 = chunk * per;
    const int e1 = (e0 + per < N_EDGES) ? e0 + per : N_EDGES;
    const int lo = win * NODES_PER_WIN;
    const int hi = lo + NODES_PER_WIN;
    for (int e = e0 + (int)threadIdx.x; e < e1; e += blockDim.x) {
        int d = dst[e];
        if (d >= lo && d < hi) {
            int p = atomicAdd(&cursor[d], 1);
            esrc[p] = src[e];
        }
    }
}

// ---- Fused GIN layer ----
// Wave (64 lanes) = 8 edge-slots (es) x 8 feature-quads (fq). One gather
// instruction moves 8 edges x 128B. W lives in registers: each lane holds the
// 4x4 fragment W[es*4+k][fq*4+c]. Each wave owns a contiguous 8-node range.
template <bool RELU, bool POOL>
__global__ void gin_layer_kernel(const float* __restrict__ x,
                                 const int* __restrict__ esrc,
                                 const int* __restrict__ rend,
                                 const int* __restrict__ deg,
                                 const float* __restrict__ W,
                                 const float* __restrict__ b,
                                 const int* __restrict__ graph_ids,
                                 float* __restrict__ out) {
    const int lane = threadIdx.x & 63;
    const int es = lane >> 3;
    const int fq = lane & 7;

    float w[4][4];
#pragma unroll
    for (int k = 0; k < 4; ++k) {
        const float4 wv = *reinterpret_cast<const float4*>(&W[(es * 4 + k) * D + fq * 4]);
        w[k][0] = wv.x; w[k][1] = wv.y; w[k][2] = wv.z; w[k][3] = wv.w;
    }
    const float4 bv = *reinterpret_cast<const float4*>(&b[fq * 4]);

    const int wid = blockIdx.x * (blockDim.x >> 6) + (threadIdx.x >> 6);
    const int v0 = wid * NODES_PER_WAVE;
    if (v0 >= N_NODES) return;
    const int v1 = (v0 + NODES_PER_WAVE < N_NODES) ? v0 + NODES_PER_WAVE : N_NODES;

    float p0 = 0.f, p1 = 0.f, p2 = 0.f, p3 = 0.f;   // pool accumulator
    int cur_g = POOL ? graph_ids[v0] : 0;

    for (int v = v0; v < v1; ++v) {
        const int end = rend[v];
        const int dg = deg[v];
        int e = end - dg;

        float a0, a1, a2, a3;
        if (es == 0) {   // self term (eps = 0)
            const float4 xv = *reinterpret_cast<const float4*>(&x[(size_t)v * D + fq * 4]);
            a0 = xv.x; a1 = xv.y; a2 = xv.z; a3 = xv.w;
        } else { a0 = a1 = a2 = a3 = 0.f; }

        // 16 edges in flight per iteration (2 x 8-edge gathers)
        for (; e + 16 <= end; e += 16) {
            const int s0 = esrc[e + es];
            const int s1 = esrc[e + 8 + es];
            const float4 g0 = *reinterpret_cast<const float4*>(&x[(size_t)s0 * D + fq * 4]);
            const float4 g1 = *reinterpret_cast<const float4*>(&x[(size_t)s1 * D + fq * 4]);
            a0 += g0.x; a1 += g0.y; a2 += g0.z; a3 += g0.w;
            a0 += g1.x; a1 += g1.y; a2 += g1.z; a3 += g1.w;
        }
        if (e + 8 <= end) {
            const int s0 = esrc[e + es];
            const float4 g0 = *reinterpret_cast<const float4*>(&x[(size_t)s0 * D + fq * 4]);
            a0 += g0.x; a1 += g0.y; a2 += g0.z; a3 += g0.w;
            e += 8;
        }
        const int rem = end - e;   // 0..7
        if (es < rem) {
            const int s0 = esrc[e + es];
            const float4 g0 = *reinterpret_cast<const float4*>(&x[(size_t)s0 * D + fq * 4]);
            a0 += g0.x; a1 += g0.y; a2 += g0.z; a3 += g0.w;
        }

        // reduce partials across es-groups (flip lane bits 3..5)
        a0 += __shfl_xor(a0, 8);  a1 += __shfl_xor(a1, 8);  a2 += __shfl_xor(a2, 8);  a3 += __shfl_xor(a3, 8);
        a0 += __shfl_xor(a0, 16); a1 += __shfl_xor(a1, 16); a2 += __shfl_xor(a2, 16); a3 += __shfl_xor(a3, 16);
        a0 += __shfl_xor(a0, 32); a1 += __shfl_xor(a1, 32); a2 += __shfl_xor(a2, 32); a3 += __shfl_xor(a3, 32);

        // group es grabs input-quad es (held by the lane with fq == es)
        const float q0 = __shfl(a0, es, 8);
        const float q1 = __shfl(a1, es, 8);
        const float q2 = __shfl(a2, es, 8);
        const float q3 = __shfl(a3, es, 8);

        // partial matvec: contribution of input rows es*4..es*4+3 to out quad fq
        float y0 = q0 * w[0][0] + q1 * w[1][0] + q2 * w[2][0] + q3 * w[3][0];
        float y1 = q0 * w[0][1] + q1 * w[1][1] + q2 * w[2][1] + q3 * w[3][1];
        float y2 = q0 * w[0][2] + q1 * w[1][2] + q2 * w[2][2] + q3 * w[3][2];
        float y3 = q0 * w[0][3] + q1 * w[1][3] + q2 * w[2][3] + q3 * w[3][3];

        y0 += __shfl_xor(y0, 8);  y1 += __shfl_xor(y1, 8);  y2 += __shfl_xor(y2, 8);  y3 += __shfl_xor(y3, 8);
        y0 += __shfl_xor(y0, 16); y1 += __shfl_xor(y1, 16); y2 += __shfl_xor(y2, 16); y3 += __shfl_xor(y3, 16);
        y0 += __shfl_xor(y0, 32); y1 += __shfl_xor(y1, 32); y2 += __shfl_xor(y2, 32); y3 += __shfl_xor(y3, 32);

        y0 += bv.x; y1 += bv.y; y2 += bv.z; y3 += bv.w;
        if (RELU) {
            y0 = fmaxf(y0, 0.f); y1 = fmaxf(y1, 0.f); y2 = fmaxf(y2, 0.f); y3 = fmaxf(y3, 0.f);
        }

        if (POOL) {
            const int g = graph_ids[v];
            if (g != cur_g) {
                if (es == 0) {
                    atomicAdd(&out[cur_g * D + fq * 4 + 0], p0);
                    atomicAdd(&out[cur_g * D + fq * 4 + 1], p1);
                    atomicAdd(&out[cur_g * D + fq * 4 + 2], p2);
                    atomicAdd(&out[cur_g * D + fq * 4 + 3], p3);
                }
                p0 = p1 = p2 = p3 = 0.f;
                cur_g = g;
            }
            p0 += y0; p1 += y1; p2 += y2; p3 += y3;
        } else {
            if (es == 0) {
                float4 o; o.x = y0; o.y = y1; o.z = y2; o.w = y3;
                *reinterpret_cast<float4*>(&out[(size_t)v * D + fq * 4]) = o;
            }
        }
    }
    if (POOL) {
        if (es == 0) {
            atomicAdd(&out[cur_g * D + fq * 4 + 0], p0);
            atomicAdd(&out[cur_g * D + fq * 4 + 1], p1);
            atomicAdd(&out[cur_g * D + fq * 4 + 2], p2);
            atomicAdd(&out[cur_g * D + fq * 4 + 3], p3);
        }
    }
}

extern "C" void kernel_launch(void* const* d_in, const int* in_sizes, int n_in,
                              void* d_out, int out_size, void* d_ws, size_t ws_size,
                              hipStream_t stream) {
    const float* feats = (const float*)d_in[0];
    const int* src = (const int*)d_in[1];
    const int* dst = (const int*)d_in[2];
    const int* graph_ids = (const int*)d_in[3];
    const float* W1 = (const float*)d_in[4];
    const float* b1 = (const float*)d_in[5];
    const float* W2 = (const float*)d_in[6];
    const float* b2 = (const float*)d_in[7];
    float* out = (float*)d_out;

    int* deg    = (int*)d_ws;                     // N_NODES
    int* inc    = deg + N_NODES;                  // N_NODES (row end)
    int* cursor = inc + N_NODES;                  // N_NODES
    int* psum   = cursor + N_NODES;               // 256
    int* esrc   = psum + 256;                     // N_EDGES
    float* h    = (float*)(esrc + N_EDGES);       // N_NODES * D

    const int edge_blocks = (N_EDGES + 255) / 256;
    const int scan3_blocks = (N_NODES + 255) / 256;
    const int total_waves = (N_NODES + NODES_PER_WAVE - 1) / NODES_PER_WAVE;  // 12500
    const int layer_blocks = (total_waves + 3) / 4;                            // 4 waves/block

    // ---- Build CSR (dst-sorted), reused by both layers ----
    hipMemsetAsync(deg, 0, (size_t)N_NODES * sizeof(int), stream);
    hist_kernel<<<edge_blocks, 256, 0, stream>>>(dst, deg);
    scan1_kernel<<<N_CHUNKS, 256, 0, stream>>>(deg, inc, psum);
    scan23_kernel<<<scan3_blocks, 256, 0, stream>>>(inc, deg, psum, cursor);
    reorder_win_kernel<<<256 * NWIN, 256, 0, stream>>>(src, dst, cursor, esrc);

    // ---- Layer 1: h = relu((x + agg(x)) @ W1 + b1) ----
    gin_layer_kernel<true, false><<<layer_blocks, 256, 0, stream>>>(
        feats, esrc, inc, deg, W1, b1, graph_ids, h);

    // ---- Layer 2 + sum pooling ----
    hipMemsetAsync(out, 0, (size_t)out_size * sizeof(float), stream);
    gin_layer_kernel<false, true><<<layer_blocks, 256, 0, stream>>>(
        h, esrc, inc, deg, W2, b2, graph_ids, out);
}